// Round 7
// baseline (276.189 us; speedup 1.0000x reference)
//
#include <hip/hip_runtime.h>
#include <hip/hip_fp16.h>

#define NPOS   4096
#define CDIM   512
#define CQK    64
#define NBATCH 4
#define L2E 1.44269504088896f

typedef _Float16 f16x8 __attribute__((ext_vector_type(8)));
typedef _Float16 f16x4 __attribute__((ext_vector_type(4)));
typedef float    f32x4 __attribute__((ext_vector_type(4)));
typedef float    f32x16 __attribute__((ext_vector_type(16)));

// LDS-only drain barrier: keeps global-load (vmcnt) prefetches in flight across
// the barrier (T4). All cross-wave traffic here is LDS, so lgkmcnt(0) suffices.
#define LDS_BARRIER() asm volatile("s_waitcnt lgkmcnt(0)\ns_barrier" ::: "memory")

// ---------------- x convert+transpose: x[b,c,n] f32 -> Xt[b,n,c] f16 ----------------
__global__ __launch_bounds__(256) void x_cvt_kernel(
    const float* __restrict__ x, _Float16* __restrict__ Xt)
{
    __shared__ _Float16 tile[64][66];
    const int b  = blockIdx.z;
    const int c0 = blockIdx.y * 64;
    const int n0 = blockIdx.x * 64;
    const int tid = threadIdx.x;

    const int rr = tid >> 4;
    const int n4 = (tid & 15) * 4;
#pragma unroll
    for (int i = 0; i < 4; ++i) {
        const int c = i * 16 + rr;
        const float4 v = *reinterpret_cast<const float4*>(
            x + (size_t)(b * CDIM + c0 + c) * NPOS + n0 + n4);
        tile[c][n4 + 0] = (_Float16)v.x;
        tile[c][n4 + 1] = (_Float16)v.y;
        tile[c][n4 + 2] = (_Float16)v.z;
        tile[c][n4 + 3] = (_Float16)v.w;
    }
    __syncthreads();

    const int col = tid & 63;
    const int r4  = tid >> 6;
#pragma unroll
    for (int i = 0; i < 16; ++i) {
        const int n = i * 4 + r4;
        Xt[((size_t)b * NPOS + n0 + n) * CDIM + c0 + col] = tile[col][n];
    }
}

// ---------------- weight convert ----------------
__global__ __launch_bounds__(256) void w_cvt_kernel(
    const float* __restrict__ wq, const float* __restrict__ bq,
    const float* __restrict__ wk, const float* __restrict__ bk,
    const float* __restrict__ wv, const float* __restrict__ bv,
    _Float16* __restrict__ Wh, float* __restrict__ biasc)
{
    const int gid = blockIdx.x * 256 + threadIdx.x;
    const int idx = gid * 4;
    const float* src;
    if (idx < 64 * 512)       src = wq + idx;
    else if (idx < 128 * 512) src = wk + (idx - 64 * 512);
    else                      src = wv + (idx - 128 * 512);
    const float4 v = *reinterpret_cast<const float4*>(src);
    f16x4 h;
    h[0] = (_Float16)v.x; h[1] = (_Float16)v.y;
    h[2] = (_Float16)v.z; h[3] = (_Float16)v.w;
    *reinterpret_cast<f16x4*>(Wh + idx) = h;
    if (gid < 640) {
        float bb;
        if (gid < 64)       bb = bq[gid];
        else if (gid < 128) bb = bk[gid - 64];
        else                bb = bv[gid - 128];
        biasc[gid] = bb;
    }
}

// ---------------- fused QKV projection GEMM (register-double-buffered) ----------------
__global__ __launch_bounds__(256) void proj_gemm_kernel(
    const _Float16* __restrict__ Wh, const float* __restrict__ biasc,
    const _Float16* __restrict__ Xt,
    _Float16* __restrict__ Qp, _Float16* __restrict__ Kp, _Float16* __restrict__ Vp)
{
    const int tid  = threadIdx.x;
    const int lane = tid & 63;
    const int w    = tid >> 6;
    const int g    = lane >> 4;
    const int lr   = lane & 15;

    const int b  = blockIdx.z;
    const int mt = blockIdx.y;
    const int m0 = mt * 64;
    const int n0 = blockIdx.x * 256 + w * 64;

    const _Float16* xb = Xt + (size_t)b * NPOS * CDIM;

    f32x4 acc[4][4];
#pragma unroll
    for (int it = 0; it < 4; ++it)
#pragma unroll
        for (int ct = 0; ct < 4; ++ct) {
            f32x4 z = {0.f, 0.f, 0.f, 0.f};
            acc[it][ct] = z;
        }

    f16x8 a0[4], b0[4], a1[4], b1[4];
    auto loadAB = [&](int kk, f16x8 (&a)[4], f16x8 (&bf)[4]) {
#pragma unroll
        for (int it = 0; it < 4; ++it)
            a[it] = *reinterpret_cast<const f16x8*>(
                Wh + (size_t)(m0 + it * 16 + lr) * CDIM + kk + 8 * g);
#pragma unroll
        for (int ct = 0; ct < 4; ++ct)
            bf[ct] = *reinterpret_cast<const f16x8*>(
                xb + (size_t)(n0 + ct * 16 + lr) * CDIM + kk + 8 * g);
    };
    auto mm16 = [&](f16x8 (&a)[4], f16x8 (&bf)[4]) {
#pragma unroll
        for (int it = 0; it < 4; ++it)
#pragma unroll
            for (int ct = 0; ct < 4; ++ct)
                acc[it][ct] = __builtin_amdgcn_mfma_f32_16x16x32_f16(a[it], bf[ct], acc[it][ct], 0, 0, 0);
    };

    loadAB(0, a0, b0);
#pragma unroll 1
    for (int p = 0; p < 8; ++p) {
        const int kk = p * 64;
        loadAB(kk + 32, a1, b1);
        mm16(a0, b0);
        if (p < 7) loadAB(kk + 64, a0, b0);
        mm16(a1, b1);
    }

    if (mt < 2) {
        _Float16* dst = (mt == 0) ? Qp : Kp;
#pragma unroll
        for (int it = 0; it < 4; ++it) {
            const int ob = it * 16 + 4 * g;
#pragma unroll
            for (int ct = 0; ct < 4; ++ct) {
                const int n = n0 + ct * 16 + lr;
                f16x4 h;
#pragma unroll
                for (int r = 0; r < 4; ++r)
                    h[r] = (_Float16)(acc[it][ct][r] + biasc[m0 + ob + r]);
                *reinterpret_cast<f16x4*>(dst + ((size_t)b * NPOS + n) * CQK + ob) = h;
            }
        }
    } else {
#pragma unroll
        for (int it = 0; it < 4; ++it)
#pragma unroll
            for (int ct = 0; ct < 4; ++ct) {
                const int n = n0 + ct * 16 + lr;
#pragma unroll
                for (int r = 0; r < 4; ++r) {
                    const int c = m0 - 128 + it * 16 + 4 * g + r;
                    Vp[((size_t)b * CDIM + c) * NPOS + n] =
                        (_Float16)(acc[it][ct][r] + biasc[m0 + it * 16 + 4 * g + r]);
                }
            }
    }
}

// ---------------- Pass 2: row max + sum(exp) of energy ----------------
// 512 threads / 8 waves, wave w owns j-slice w*16 of each 128-j chunk.
// E per (i,j) is the same two-MFMA chain on the same Q/K frags as attn_out
// -> bitwise-identical E -> exp(E-m) <= 1 exactly in pass 3.
__global__ __launch_bounds__(512, 2) void attn_stats_kernel(
    const _Float16* __restrict__ Qp, const _Float16* __restrict__ Kp,
    float* __restrict__ mOut, float* __restrict__ lOut)
{
    __shared__ float lm[8 * 64];
    __shared__ float ls[8 * 64];

    const int tid  = threadIdx.x;
    const int lane = tid & 63;
    const int w    = tid >> 6;      // 0..7
    const int g    = lane >> 4;
    const int lr   = lane & 15;
    const int b    = blockIdx.y;
    const int ib   = blockIdx.x * 64;

    f16x8 qf[4][2];
#pragma unroll
    for (int it = 0; it < 4; ++it)
#pragma unroll
        for (int ks = 0; ks < 2; ++ks)
            qf[it][ks] = *reinterpret_cast<const f16x8*>(
                Qp + (b * NPOS + ib + it * 16 + lr) * CQK + ks * 32 + 8 * g);

    const _Float16* kb = Kp + (size_t)b * NPOS * CQK;

    float mrun[4][4], srun[4][4];
#pragma unroll
    for (int it = 0; it < 4; ++it)
#pragma unroll
        for (int r = 0; r < 4; ++r) { mrun[it][r] = -1e30f; srun[it][r] = 0.f; }

    f16x8 kA0, kA1, kB0, kB1;
    auto loadK = [&](int t, f16x8& k0, f16x8& k1) {
        const int j = t * 128 + w * 16 + lr;
        k0 = *reinterpret_cast<const f16x8*>(kb + j * CQK + 8 * g);
        k1 = *reinterpret_cast<const f16x8*>(kb + j * CQK + 32 + 8 * g);
    };
    auto step = [&](const f16x8& k0, const f16x8& k1) {
#pragma unroll
        for (int it = 0; it < 4; ++it) {
            f32x4 e = {0.f, 0.f, 0.f, 0.f};
            e = __builtin_amdgcn_mfma_f32_16x16x32_f16(qf[it][0], k0, e, 0, 0, 0);
            e = __builtin_amdgcn_mfma_f32_16x16x32_f16(qf[it][1], k1, e, 0, 0, 0);
#pragma unroll
            for (int r = 0; r < 4; ++r) {
                const float ev = e[r];
                const float mo = mrun[it][r];
                if (ev > mo) {
                    srun[it][r] = srun[it][r] * exp2f((mo - ev) * L2E) + 1.0f;
                    mrun[it][r] = ev;
                } else {
                    srun[it][r] += exp2f((ev - mo) * L2E);
                }
            }
        }
    };

    loadK(0, kA0, kA1);
#pragma unroll 1
    for (int tp = 0; tp < 16; ++tp) {
        const int t = 2 * tp;
        loadK(t + 1, kB0, kB1);
        step(kA0, kA1);
        const int tn = (t + 2 < 32) ? t + 2 : 31;
        loadK(tn, kA0, kA1);
        step(kB0, kB1);
    }

#pragma unroll
    for (int it = 0; it < 4; ++it) {
#pragma unroll
        for (int r = 0; r < 4; ++r) {
            float m = mrun[it][r], s = srun[it][r];
#pragma unroll
            for (int mask = 1; mask < 16; mask <<= 1) {
                float om = __shfl_xor(m, mask, 64);
                float os = __shfl_xor(s, mask, 64);
                float mn = fmaxf(m, om);
                s = s * exp2f((m - mn) * L2E) + os * exp2f((om - mn) * L2E);
                m = mn;
            }
            if (lr == 0) {
                const int row = it * 16 + 4 * g + r;
                lm[w * 64 + row] = m;
                ls[w * 64 + row] = s;
            }
        }
    }
    __syncthreads();

    if (tid < 64) {
        float mm = lm[tid];
#pragma unroll
        for (int w2 = 1; w2 < 8; ++w2) mm = fmaxf(mm, lm[w2 * 64 + tid]);
        float ss = 0.f;
#pragma unroll
        for (int w2 = 0; w2 < 8; ++w2) ss += ls[w2 * 64 + tid] * exp2f((lm[w2 * 64 + tid] - mm) * L2E);
        mOut[b * NPOS + ib + tid] = mm;
        lOut[b * NPOS + ib + tid] = ss;
    }
}

// ---------------- Pass 3: pipelined flash PV ----------------
// Block: 64 q-rows x 256 c (half = bid&1), 8 waves. E phase 16x16 (bitwise-identical
// to attn_stats); PV phase 32x32x16 (higher-ceiling pipe, half the instructions).
// Wave-parity stagger: even waves run [PV -> E], odd waves [E -> PV] within each
// inter-barrier region, so the MFMA pipe and the VALU/exp pipe stay simultaneously
// fed instead of all waves hitting the same phase in lockstep.
// launch_bounds (512,2): measured-good codegen (VGPR<=128, no spills — R3/R6).
// A min-waves arg of 4 forces VGPR=64 and catastrophic spills (R4/R5).
__global__ __launch_bounds__(512, 2) void attn_out_kernel(
    const float* __restrict__ x, const _Float16* __restrict__ Qp, const _Float16* __restrict__ Kp,
    const _Float16* __restrict__ Vp, const float* __restrict__ mArr, const float* __restrict__ lArr,
    const float* __restrict__ gamma, float* __restrict__ out)
{
    __shared__ __align__(16) _Float16 Pl[2][64 * 128];   // 32 KB
    char* pb0 = (char*)Pl[0];
    char* pb1 = (char*)Pl[1];

    const int tid  = threadIdx.x;
    const int lane = tid & 63;
    const int w    = tid >> 6;      // 0..7
    const int g    = lane >> 4;     // 0..3
    const int lr   = lane & 15;
    const int l31  = lane & 31;     // 32x32 row/col index
    const int hi   = lane >> 5;     // 0..1

    const int bid  = blockIdx.x;            // [0, 512)
    const int b    = (bid & 7) >> 1;        // batch -> XCD pair {2b, 2b+1}
    const int half = bid & 1;               // c-half (one per XCD of the pair)
    const int ib   = (bid >> 3) * 64;
    const int cw   = half * 256 + w * 32;   // wave's 32-c slice

    const _Float16* kb = Kp + (size_t)b * NPOS * CQK;
    const _Float16* vb = Vp + (size_t)b * CDIM * NPOS;

    f16x8 qf[4][2];
#pragma unroll
    for (int it = 0; it < 4; ++it)
#pragma unroll
        for (int ks = 0; ks < 2; ++ks)
            qf[it][ks] = *reinterpret_cast<const f16x8*>(
                Qp + (b * NPOS + ib + it * 16 + lr) * CQK + ks * 32 + 8 * g);

    float mreg[4][4];
#pragma unroll
    for (int it = 0; it < 4; ++it) {
        const float4 mv = *reinterpret_cast<const float4*>(
            mArr + b * NPOS + ib + it * 16 + 4 * g);
        mreg[it][0] = mv.x; mreg[it][1] = mv.y; mreg[it][2] = mv.z; mreg[it][3] = mv.w;
    }

    f32x16 acc2[2];
    {
        f32x16 z = {};
        acc2[0] = z; acc2[1] = z;
    }

    f16x8 vreg[8];                  // V B-frags for the chunk being PV'd (32 VGPR)
    f16x8 kA0, kA1, kB0, kB1;       // 2-slot K prefetch

    auto loadK = [&](int t, f16x8& k0, f16x8& k1) {
        const int j = t * 128 + w * 16 + lr;
        k0 = *reinterpret_cast<const f16x8*>(kb + j * CQK + 8 * g);
        k1 = *reinterpret_cast<const f16x8*>(kb + j * CQK + 32 + 8 * g);
    };
    // V B-frag (32x32x16): col c = cw + l31, k = 8*hi + t -> j = jb + ks2*16 + 8*hi + t
    auto loadV = [&](int t) {
        const int jb = t * 128;
        const _Float16* vrow = vb + (size_t)(cw + l31) * NPOS + jb + 8 * hi;
#pragma unroll
        for (int ks2 = 0; ks2 < 8; ++ks2)
            vreg[ks2] = *reinterpret_cast<const f16x8*>(vrow + ks2 * 16);
    };
    // E phase: identical MFMA chain to attn_stats -> identical E -> exp(E-m) <= 1.
    auto ephase = [&](const f16x8& k0, const f16x8& k1, char* dst) {
#pragma unroll
        for (int it = 0; it < 4; ++it) {
            f32x4 e = {0.f, 0.f, 0.f, 0.f};
            e = __builtin_amdgcn_mfma_f32_16x16x32_f16(qf[it][0], k0, e, 0, 0, 0);
            e = __builtin_amdgcn_mfma_f32_16x16x32_f16(qf[it][1], k1, e, 0, 0, 0);
#pragma unroll
            for (int r = 0; r < 4; ++r) {
                const _Float16 p = (_Float16)exp2f((e[r] - mreg[it][r]) * L2E);
                const int i   = it * 16 + 4 * g + r;
                const int off = (i * 256 + (w * 16 + lr) * 2) ^ ((i & 15) << 4);
                *reinterpret_cast<_Float16*>(dst + off) = p;
            }
        }
    };
    // PV phase: 32x32x16. A = P rows (i = it*32 + l31), k = 8*hi + t.
    // Byte offset = row*256 + ((ks2*32 + 16*hi) ^ ((row&15)<<4)); row&15 == lane&15.
    auto pvphase = [&](const char* src) {
        __builtin_amdgcn_s_setprio(1);
#pragma unroll
        for (int ks2 = 0; ks2 < 8; ++ks2) {
            const int col = (ks2 * 32 + 16 * hi) ^ ((lane & 15) << 4);
            f16x8 pa0 = *reinterpret_cast<const f16x8*>(src + (l31 * 256 + col));
            f16x8 pa1 = *reinterpret_cast<const f16x8*>(src + ((32 + l31) * 256 + col));
            acc2[0] = __builtin_amdgcn_mfma_f32_32x32x16_f16(pa0, vreg[ks2], acc2[0], 0, 0, 0);
            acc2[1] = __builtin_amdgcn_mfma_f32_32x32x16_f16(pa1, vreg[ks2], acc2[1], 0, 0, 0);
        }
        __builtin_amdgcn_s_setprio(0);
    };

    // Prologue: P(0) into buf0, V(0) into regs, K(1) prefetched.
    loadK(0, kA0, kA1);
    ephase(kA0, kA1, pb0);
    loadV(0);
    loadK(1, kB0, kB1);
    __syncthreads();

#pragma unroll 1
    for (int tp = 0; tp < 15; ++tp) {
        const int t = 2 * tp;
        // chunk t (even): PV from buf0; E(t+1) -> buf1 (uses K(t+1) = kB)
        if ((w & 1) == 0) {
            pvphase(pb0);
            loadV(t + 1);
            ephase(kB0, kB1, pb1);
            loadK(t + 2, kA0, kA1);
        } else {
            ephase(kB0, kB1, pb1);
            loadK(t + 2, kA0, kA1);
            pvphase(pb0);
            loadV(t + 1);
        }
        LDS_BARRIER();
        // chunk t+1 (odd): PV from buf1; E(t+2) -> buf0 (uses K(t+2) = kA)
        if ((w & 1) == 0) {
            pvphase(pb1);
            loadV(t + 2);
            ephase(kA0, kA1, pb0);
            loadK((t + 3 < 32) ? t + 3 : 31, kB0, kB1);
        } else {
            ephase(kA0, kA1, pb0);
            loadK((t + 3 < 32) ? t + 3 : 31, kB0, kB1);
            pvphase(pb1);
            loadV(t + 2);
        }
        LDS_BARRIER();
    }
    // tail: t = 30, 31
    pvphase(pb0);
    loadV(31);
    ephase(kB0, kB1, pb1);              // P(31), K(31) = kB
    LDS_BARRIER();
    pvphase(pb1);

    // ---- epilogue: out = gamma * acc / l + x ----
    // 32x32 C/D layout: col = lane&31 -> c; row = (reg&3) + 8*(reg>>2) + 4*hi.
    const float gm = gamma[0];
    const int c = cw + l31;
#pragma unroll
    for (int it = 0; it < 2; ++it) {
#pragma unroll
        for (int q = 0; q < 4; ++q) {
            const int i0 = ib + it * 32 + 8 * q + 4 * hi;
            const float4 lv = *reinterpret_cast<const float4*>(lArr + b * NPOS + i0);
            const size_t base = (size_t)(b * CDIM + c) * NPOS + i0;
            const float4 xv = *reinterpret_cast<const float4*>(x + base);
            float4 ov;
            ov.x = gm * (acc2[it][4 * q + 0] / lv.x) + xv.x;
            ov.y = gm * (acc2[it][4 * q + 1] / lv.y) + xv.y;
            ov.z = gm * (acc2[it][4 * q + 2] / lv.z) + xv.z;
            ov.w = gm * (acc2[it][4 * q + 3] / lv.w) + xv.w;
            *reinterpret_cast<float4*>(out + base) = ov;
        }
    }
}

extern "C" void kernel_launch(void* const* d_in, const int* in_sizes, int n_in,
                              void* d_out, int out_size, void* d_ws, size_t ws_size,
                              hipStream_t stream)
{
    (void)in_sizes; (void)n_in; (void)out_size; (void)ws_size;

    const float* x     = (const float*)d_in[0];
    const float* wq    = (const float*)d_in[1];
    const float* bq    = (const float*)d_in[2];
    const float* wk    = (const float*)d_in[3];
    const float* bk    = (const float*)d_in[4];
    const float* wv    = (const float*)d_in[5];
    const float* bv    = (const float*)d_in[6];
    const float* gamma = (const float*)d_in[7];
    float* out = (float*)d_out;

    char* ws = (char*)d_ws;
    const size_t qkBytes = (size_t)NBATCH * NPOS * CQK * sizeof(_Float16);   //  2 MiB each
    const size_t vBytes  = (size_t)NBATCH * CDIM * NPOS * sizeof(_Float16);  // 16 MiB
    const size_t mlBytes = (size_t)NBATCH * NPOS * sizeof(float);            // 64 KiB each
    const size_t xtBytes = (size_t)NBATCH * NPOS * CDIM * sizeof(_Float16);  // 16 MiB

    _Float16* Qp = (_Float16*)(ws);
    _Float16* Kp = (_Float16*)(ws + qkBytes);
    _Float16* Vp = (_Float16*)(ws + 2 * qkBytes);
    float* mArr  = (float*)(ws + 2 * qkBytes + vBytes);
    float* lArr  = (float*)(ws + 2 * qkBytes + vBytes + mlBytes);
    _Float16* Xt = (_Float16*)(ws + 2 * qkBytes + vBytes + 2 * mlBytes);
    _Float16* Wh = (_Float16*)(ws + 2 * qkBytes + vBytes + 2 * mlBytes + xtBytes);
    float* biasc = (float*)(ws + 2 * qkBytes + vBytes + 2 * mlBytes + xtBytes
                              + (size_t)640 * CDIM * sizeof(_Float16));

    w_cvt_kernel<<<dim3(640 * CDIM / 4 / 256), 256, 0, stream>>>(wq, bq, wk, bk, wv, bv, Wh, biasc);
    x_cvt_kernel<<<dim3(NPOS / 64, CDIM / 64, NBATCH), 256, 0, stream>>>(x, Xt);
    proj_gemm_kernel<<<dim3(NPOS / 256, 10, NBATCH), 256, 0, stream>>>(Wh, biasc, Xt, Qp, Kp, Vp);
    attn_stats_kernel<<<dim3(NPOS / 64, NBATCH), 512, 0, stream>>>(Qp, Kp, mArr, lArr);
    attn_out_kernel<<<dim3(NPOS / 64 * 2 * NBATCH), 512, 0, stream>>>(x, Qp, Kp, Vp, mArr, lArr, gamma, out);
}

// Round 8
// 259.497 us; speedup vs baseline: 1.0643x; 1.0643x over previous
//
#include <hip/hip_runtime.h>
#include <hip/hip_fp16.h>

#define NPOS   4096
#define CDIM   512
#define CQK    64
#define NBATCH 4
#define L2E 1.44269504088896f

typedef _Float16 f16x8 __attribute__((ext_vector_type(8)));
typedef _Float16 f16x4 __attribute__((ext_vector_type(4)));
typedef float    f32x4 __attribute__((ext_vector_type(4)));

// LDS-only drain barrier: keeps global-load (vmcnt) prefetches in flight across
// the barrier (T4). All cross-wave traffic here is LDS, so lgkmcnt(0) suffices.
#define LDS_BARRIER() asm volatile("s_waitcnt lgkmcnt(0)\ns_barrier" ::: "memory")

// ---------------- x convert+transpose: x[b,c,n] f32 -> Xt[b,n,c] f16 ----------------
__global__ __launch_bounds__(256) void x_cvt_kernel(
    const float* __restrict__ x, _Float16* __restrict__ Xt)
{
    __shared__ _Float16 tile[64][66];
    const int b  = blockIdx.z;
    const int c0 = blockIdx.y * 64;
    const int n0 = blockIdx.x * 64;
    const int tid = threadIdx.x;

    const int rr = tid >> 4;
    const int n4 = (tid & 15) * 4;
#pragma unroll
    for (int i = 0; i < 4; ++i) {
        const int c = i * 16 + rr;
        const float4 v = *reinterpret_cast<const float4*>(
            x + (size_t)(b * CDIM + c0 + c) * NPOS + n0 + n4);
        tile[c][n4 + 0] = (_Float16)v.x;
        tile[c][n4 + 1] = (_Float16)v.y;
        tile[c][n4 + 2] = (_Float16)v.z;
        tile[c][n4 + 3] = (_Float16)v.w;
    }
    __syncthreads();

    const int col = tid & 63;
    const int r4  = tid >> 6;
#pragma unroll
    for (int i = 0; i < 16; ++i) {
        const int n = i * 4 + r4;
        Xt[((size_t)b * NPOS + n0 + n) * CDIM + c0 + col] = tile[col][n];
    }
}

// ---------------- weight convert ----------------
__global__ __launch_bounds__(256) void w_cvt_kernel(
    const float* __restrict__ wq, const float* __restrict__ bq,
    const float* __restrict__ wk, const float* __restrict__ bk,
    const float* __restrict__ wv, const float* __restrict__ bv,
    _Float16* __restrict__ Wh, float* __restrict__ biasc)
{
    const int gid = blockIdx.x * 256 + threadIdx.x;
    const int idx = gid * 4;
    const float* src;
    if (idx < 64 * 512)       src = wq + idx;
    else if (idx < 128 * 512) src = wk + (idx - 64 * 512);
    else                      src = wv + (idx - 128 * 512);
    const float4 v = *reinterpret_cast<const float4*>(src);
    f16x4 h;
    h[0] = (_Float16)v.x; h[1] = (_Float16)v.y;
    h[2] = (_Float16)v.z; h[3] = (_Float16)v.w;
    *reinterpret_cast<f16x4*>(Wh + idx) = h;
    if (gid < 640) {
        float bb;
        if (gid < 64)       bb = bq[gid];
        else if (gid < 128) bb = bk[gid - 64];
        else                bb = bv[gid - 128];
        biasc[gid] = bb;
    }
}

// ---------------- fused QKV projection GEMM (register-double-buffered) ----------------
__global__ __launch_bounds__(256) void proj_gemm_kernel(
    const _Float16* __restrict__ Wh, const float* __restrict__ biasc,
    const _Float16* __restrict__ Xt,
    _Float16* __restrict__ Qp, _Float16* __restrict__ Kp, _Float16* __restrict__ Vp)
{
    const int tid  = threadIdx.x;
    const int lane = tid & 63;
    const int w    = tid >> 6;
    const int g    = lane >> 4;
    const int lr   = lane & 15;

    const int b  = blockIdx.z;
    const int mt = blockIdx.y;
    const int m0 = mt * 64;
    const int n0 = blockIdx.x * 256 + w * 64;

    const _Float16* xb = Xt + (size_t)b * NPOS * CDIM;

    f32x4 acc[4][4];
#pragma unroll
    for (int it = 0; it < 4; ++it)
#pragma unroll
        for (int ct = 0; ct < 4; ++ct) {
            f32x4 z = {0.f, 0.f, 0.f, 0.f};
            acc[it][ct] = z;
        }

    f16x8 a0[4], b0[4], a1[4], b1[4];
    auto loadAB = [&](int kk, f16x8 (&a)[4], f16x8 (&bf)[4]) {
#pragma unroll
        for (int it = 0; it < 4; ++it)
            a[it] = *reinterpret_cast<const f16x8*>(
                Wh + (size_t)(m0 + it * 16 + lr) * CDIM + kk + 8 * g);
#pragma unroll
        for (int ct = 0; ct < 4; ++ct)
            bf[ct] = *reinterpret_cast<const f16x8*>(
                xb + (size_t)(n0 + ct * 16 + lr) * CDIM + kk + 8 * g);
    };
    auto mm16 = [&](f16x8 (&a)[4], f16x8 (&bf)[4]) {
#pragma unroll
        for (int it = 0; it < 4; ++it)
#pragma unroll
            for (int ct = 0; ct < 4; ++ct)
                acc[it][ct] = __builtin_amdgcn_mfma_f32_16x16x32_f16(a[it], bf[ct], acc[it][ct], 0, 0, 0);
    };

    loadAB(0, a0, b0);
#pragma unroll 1
    for (int p = 0; p < 8; ++p) {
        const int kk = p * 64;
        loadAB(kk + 32, a1, b1);
        mm16(a0, b0);
        if (p < 7) loadAB(kk + 64, a0, b0);
        mm16(a1, b1);
    }

    if (mt < 2) {
        _Float16* dst = (mt == 0) ? Qp : Kp;
#pragma unroll
        for (int it = 0; it < 4; ++it) {
            const int ob = it * 16 + 4 * g;
#pragma unroll
            for (int ct = 0; ct < 4; ++ct) {
                const int n = n0 + ct * 16 + lr;
                f16x4 h;
#pragma unroll
                for (int r = 0; r < 4; ++r)
                    h[r] = (_Float16)(acc[it][ct][r] + biasc[m0 + ob + r]);
                *reinterpret_cast<f16x4*>(dst + ((size_t)b * NPOS + n) * CQK + ob) = h;
            }
        }
    } else {
#pragma unroll
        for (int it = 0; it < 4; ++it)
#pragma unroll
            for (int ct = 0; ct < 4; ++ct) {
                const int n = n0 + ct * 16 + lr;
#pragma unroll
                for (int r = 0; r < 4; ++r) {
                    const int c = m0 - 128 + it * 16 + 4 * g + r;
                    Vp[((size_t)b * CDIM + c) * NPOS + n] =
                        (_Float16)(acc[it][ct][r] + biasc[m0 + it * 16 + 4 * g + r]);
                }
            }
    }
}

// ---------------- Pass 2: partial row max + sum(exp) over a j-half ----------------
// Grid (N/64, B, 2): jh = blockIdx.z selects j in [jh*2048, jh*2048+2048).
// 512 threads / 8 waves; wave w owns j-slice w*16 of each 128-j chunk.
// Per-chunk MFMA chain identical to attn_out's ephase for the same j
// -> bitwise-identical E -> exp(E - max) <= 1 exactly in pass 3.
// Partial (m,l) per half; attn_out merges the two halves.
__global__ __launch_bounds__(512, 2) void attn_stats_kernel(
    const _Float16* __restrict__ Qp, const _Float16* __restrict__ Kp,
    float* __restrict__ mOut, float* __restrict__ lOut)
{
    __shared__ float lm[8 * 64];
    __shared__ float ls[8 * 64];

    const int tid  = threadIdx.x;
    const int lane = tid & 63;
    const int w    = tid >> 6;      // 0..7
    const int g    = lane >> 4;
    const int lr   = lane & 15;
    const int b    = blockIdx.y;
    const int ib   = blockIdx.x * 64;
    const int jh   = blockIdx.z;    // j-half

    f16x8 qf[4][2];
#pragma unroll
    for (int it = 0; it < 4; ++it)
#pragma unroll
        for (int ks = 0; ks < 2; ++ks)
            qf[it][ks] = *reinterpret_cast<const f16x8*>(
                Qp + (b * NPOS + ib + it * 16 + lr) * CQK + ks * 32 + 8 * g);

    const _Float16* kb = Kp + (size_t)b * NPOS * CQK + (size_t)jh * 2048 * CQK;

    float mrun[4][4], srun[4][4];
#pragma unroll
    for (int it = 0; it < 4; ++it)
#pragma unroll
        for (int r = 0; r < 4; ++r) { mrun[it][r] = -1e30f; srun[it][r] = 0.f; }

    f16x8 kA0, kA1, kB0, kB1;
    auto loadK = [&](int t, f16x8& k0, f16x8& k1) {
        const int j = t * 128 + w * 16 + lr;
        k0 = *reinterpret_cast<const f16x8*>(kb + j * CQK + 8 * g);
        k1 = *reinterpret_cast<const f16x8*>(kb + j * CQK + 32 + 8 * g);
    };
    auto step = [&](const f16x8& k0, const f16x8& k1) {
#pragma unroll
        for (int it = 0; it < 4; ++it) {
            f32x4 e = {0.f, 0.f, 0.f, 0.f};
            e = __builtin_amdgcn_mfma_f32_16x16x32_f16(qf[it][0], k0, e, 0, 0, 0);
            e = __builtin_amdgcn_mfma_f32_16x16x32_f16(qf[it][1], k1, e, 0, 0, 0);
#pragma unroll
            for (int r = 0; r < 4; ++r) {
                const float ev = e[r];
                const float mo = mrun[it][r];
                if (ev > mo) {
                    srun[it][r] = srun[it][r] * exp2f((mo - ev) * L2E) + 1.0f;
                    mrun[it][r] = ev;
                } else {
                    srun[it][r] += exp2f((ev - mo) * L2E);
                }
            }
        }
    };

    loadK(0, kA0, kA1);
#pragma unroll 1
    for (int tp = 0; tp < 8; ++tp) {
        const int t = 2 * tp;
        loadK(t + 1, kB0, kB1);
        step(kA0, kA1);
        const int tn = (t + 2 < 16) ? t + 2 : 15;
        loadK(tn, kA0, kA1);
        step(kB0, kB1);
    }

#pragma unroll
    for (int it = 0; it < 4; ++it) {
#pragma unroll
        for (int r = 0; r < 4; ++r) {
            float m = mrun[it][r], s = srun[it][r];
#pragma unroll
            for (int mask = 1; mask < 16; mask <<= 1) {
                float om = __shfl_xor(m, mask, 64);
                float os = __shfl_xor(s, mask, 64);
                float mn = fmaxf(m, om);
                s = s * exp2f((m - mn) * L2E) + os * exp2f((om - mn) * L2E);
                m = mn;
            }
            if (lr == 0) {
                const int row = it * 16 + 4 * g + r;
                lm[w * 64 + row] = m;
                ls[w * 64 + row] = s;
            }
        }
    }
    __syncthreads();

    if (tid < 64) {
        float mm = lm[tid];
#pragma unroll
        for (int w2 = 1; w2 < 8; ++w2) mm = fmaxf(mm, lm[w2 * 64 + tid]);
        float ss = 0.f;
#pragma unroll
        for (int w2 = 0; w2 < 8; ++w2) ss += ls[w2 * 64 + tid] * exp2f((lm[w2 * 64 + tid] - mm) * L2E);
        const size_t o = ((size_t)jh * NBATCH + b) * NPOS + ib + tid;
        mOut[o] = mm;
        lOut[o] = ss;
    }
}

// ---------------- Pass 3: pipelined flash PV (R3 structure, best measured) ----------------
// Block: 64 q-rows x all 512 c, 8 waves (wave owns 64 c). Chunk = 128 j. Wave w computes
// E for j-slice w*16 (shared via double-buffered LDS P); PV with V frags one chunk ahead
// in regs. One LDS-only barrier per chunk; global prefetches stay in flight across it.
// m = max of the two j-half partial maxima (prologue); l merged in the epilogue.
// launch_bounds (512,2): measured-good codegen (VGPR=128, no spills — R3/R6). A min-waves
// arg of 4 forces VGPR=64 and catastrophic spills (R4/R5 post-mortems).
__global__ __launch_bounds__(512, 2) void attn_out_kernel(
    const float* __restrict__ x, const _Float16* __restrict__ Qp, const _Float16* __restrict__ Kp,
    const _Float16* __restrict__ Vp, const float* __restrict__ mArr, const float* __restrict__ lArr,
    const float* __restrict__ gamma, float* __restrict__ out)
{
    __shared__ __align__(16) _Float16 Pl[2][64 * 128];
    char* pb0 = (char*)Pl[0];
    char* pb1 = (char*)Pl[1];

    const int tid  = threadIdx.x;
    const int lane = tid & 63;
    const int w    = tid >> 6;      // 0..7
    const int g    = lane >> 4;     // 0..3
    const int lr   = lane & 15;

    // XCD-aware decode: batch b -> XCDs {2b,2b+1} so each XCD L2 holds one batch's V+K.
    const int bid = blockIdx.x;
    const int b   = (bid & 7) >> 1;
    const int ib  = (((bid >> 3) << 1) | (bid & 1)) * 64;
    const int cw  = w * 64;

    const _Float16* kb = Kp + (size_t)b * NPOS * CQK;
    const _Float16* vb = Vp + (size_t)b * CDIM * NPOS;

    f16x8 qf[4][2];
#pragma unroll
    for (int it = 0; it < 4; ++it)
#pragma unroll
        for (int ks = 0; ks < 2; ++ks)
            qf[it][ks] = *reinterpret_cast<const f16x8*>(
                Qp + (b * NPOS + ib + it * 16 + lr) * CQK + ks * 32 + 8 * g);

    // m = max over the two j-half partial maxima
    float mreg[4][4];
#pragma unroll
    for (int it = 0; it < 4; ++it) {
        const float4 m0 = *reinterpret_cast<const float4*>(
            mArr + (size_t)b * NPOS + ib + it * 16 + 4 * g);
        const float4 m1 = *reinterpret_cast<const float4*>(
            mArr + ((size_t)NBATCH + b) * NPOS + ib + it * 16 + 4 * g);
        mreg[it][0] = fmaxf(m0.x, m1.x); mreg[it][1] = fmaxf(m0.y, m1.y);
        mreg[it][2] = fmaxf(m0.z, m1.z); mreg[it][3] = fmaxf(m0.w, m1.w);
    }

    f32x4 acc[4][4];
#pragma unroll
    for (int it = 0; it < 4; ++it)
#pragma unroll
        for (int ct = 0; ct < 4; ++ct) {
            f32x4 z = {0.f, 0.f, 0.f, 0.f};
            acc[it][ct] = z;
        }

    f16x8 vreg[4][4];   // [ks][ct] V frags for the chunk being PV'd
    f16x8 kA0, kA1, kB0, kB1;

    auto loadK = [&](int t, f16x8& k0, f16x8& k1) {
        const int j = t * 128 + w * 16 + lr;
        k0 = *reinterpret_cast<const f16x8*>(kb + j * CQK + 8 * g);
        k1 = *reinterpret_cast<const f16x8*>(kb + j * CQK + 32 + 8 * g);
    };
    auto loadV = [&](int t) {
        const int jb = t * 128;
#pragma unroll
        for (int ks = 0; ks < 4; ++ks)
#pragma unroll
            for (int ct = 0; ct < 4; ++ct)
                vreg[ks][ct] = *reinterpret_cast<const f16x8*>(
                    vb + (size_t)(cw + ct * 16 + lr) * NPOS + jb + ks * 32 + 8 * g);
    };
    // E phase: identical MFMA chain to attn_stats -> identical E -> exp(E-m) <= 1.
    auto ephase = [&](const f16x8& k0, const f16x8& k1, char* dst) {
#pragma unroll
        for (int it = 0; it < 4; ++it) {
            f32x4 e = {0.f, 0.f, 0.f, 0.f};
            e = __builtin_amdgcn_mfma_f32_16x16x32_f16(qf[it][0], k0, e, 0, 0, 0);
            e = __builtin_amdgcn_mfma_f32_16x16x32_f16(qf[it][1], k1, e, 0, 0, 0);
#pragma unroll
            for (int r = 0; r < 4; ++r) {
                const _Float16 p = (_Float16)exp2f((e[r] - mreg[it][r]) * L2E);
                const int i   = it * 16 + 4 * g + r;
                const int off = (i * 256 + (w * 16 + lr) * 2) ^ ((i & 15) << 4);
                *reinterpret_cast<_Float16*>(dst + off) = p;
            }
        }
    };
    auto pvphase = [&](const char* src) {
        __builtin_amdgcn_s_setprio(1);
#pragma unroll
        for (int ks = 0; ks < 4; ++ks) {
            f16x8 pa[4];
#pragma unroll
            for (int it = 0; it < 4; ++it) {
                const int off = (it * 16 + lr) * 256 + ((ks * 64 + g * 16) ^ (lr << 4));
                pa[it] = *reinterpret_cast<const f16x8*>(src + off);
            }
#pragma unroll
            for (int it = 0; it < 4; ++it)
#pragma unroll
                for (int ct = 0; ct < 4; ++ct)
                    acc[it][ct] = __builtin_amdgcn_mfma_f32_16x16x32_f16(pa[it], vreg[ks][ct], acc[it][ct], 0, 0, 0);
        }
        __builtin_amdgcn_s_setprio(0);
    };

    // Prologue: P(0) into buf0, V(0) into regs, K(1) prefetched.
    loadK(0, kA0, kA1);
    ephase(kA0, kA1, pb0);
    loadV(0);
    loadK(1, kB0, kB1);
    __syncthreads();

#pragma unroll 1
    for (int tp = 0; tp < 15; ++tp) {
        const int t = 2 * tp;
        // chunk t (even): PV from buf0
        pvphase(pb0);
        loadV(t + 1);
        ephase(kB0, kB1, pb1);          // P(t+1) -> buf1 (uses K(t+1) = kB)
        loadK(t + 2, kA0, kA1);         // K(t+2) -> kA
        LDS_BARRIER();
        // chunk t+1 (odd): PV from buf1
        pvphase(pb1);
        loadV(t + 2);
        ephase(kA0, kA1, pb0);          // P(t+2) -> buf0 (uses K(t+2) = kA)
        loadK((t + 3 < 32) ? t + 3 : 31, kB0, kB1);
        LDS_BARRIER();
    }
    // tail: t = 30, 31
    pvphase(pb0);
    loadV(31);
    ephase(kB0, kB1, pb1);              // P(31), K(31) = kB
    LDS_BARRIER();
    pvphase(pb1);

    // ---- epilogue: merge j-half (m,l), then out = gamma * acc / l + x ----
    const float gm = gamma[0];
#pragma unroll
    for (int it = 0; it < 4; ++it) {
        const int idx = ib + it * 16 + 4 * g;
        const float4 m0 = *reinterpret_cast<const float4*>(mArr + (size_t)b * NPOS + idx);
        const float4 m1 = *reinterpret_cast<const float4*>(mArr + ((size_t)NBATCH + b) * NPOS + idx);
        const float4 l0 = *reinterpret_cast<const float4*>(lArr + (size_t)b * NPOS + idx);
        const float4 l1 = *reinterpret_cast<const float4*>(lArr + ((size_t)NBATCH + b) * NPOS + idx);
        float inv[4];
        {
            const float mx = fmaxf(m0.x, m1.x);
            inv[0] = 1.0f / (l0.x * exp2f((m0.x - mx) * L2E) + l1.x * exp2f((m1.x - mx) * L2E));
            const float my = fmaxf(m0.y, m1.y);
            inv[1] = 1.0f / (l0.y * exp2f((m0.y - my) * L2E) + l1.y * exp2f((m1.y - my) * L2E));
            const float mz = fmaxf(m0.z, m1.z);
            inv[2] = 1.0f / (l0.z * exp2f((m0.z - mz) * L2E) + l1.z * exp2f((m1.z - mz) * L2E));
            const float mw = fmaxf(m0.w, m1.w);
            inv[3] = 1.0f / (l0.w * exp2f((m0.w - mw) * L2E) + l1.w * exp2f((m1.w - mw) * L2E));
        }
#pragma unroll
        for (int ct = 0; ct < 4; ++ct) {
            const int c = cw + ct * 16 + lr;
            const size_t base = (size_t)(b * CDIM + c) * NPOS + idx;
            const float4 xv = *reinterpret_cast<const float4*>(x + base);
            float4 ov;
            ov.x = gm * (acc[it][ct][0] * inv[0]) + xv.x;
            ov.y = gm * (acc[it][ct][1] * inv[1]) + xv.y;
            ov.z = gm * (acc[it][ct][2] * inv[2]) + xv.z;
            ov.w = gm * (acc[it][ct][3] * inv[3]) + xv.w;
            *reinterpret_cast<float4*>(out + base) = ov;
        }
    }
}

extern "C" void kernel_launch(void* const* d_in, const int* in_sizes, int n_in,
                              void* d_out, int out_size, void* d_ws, size_t ws_size,
                              hipStream_t stream)
{
    (void)in_sizes; (void)n_in; (void)out_size; (void)ws_size;

    const float* x     = (const float*)d_in[0];
    const float* wq    = (const float*)d_in[1];
    const float* bq    = (const float*)d_in[2];
    const float* wk    = (const float*)d_in[3];
    const float* bk    = (const float*)d_in[4];
    const float* wv    = (const float*)d_in[5];
    const float* bv    = (const float*)d_in[6];
    const float* gamma = (const float*)d_in[7];
    float* out = (float*)d_out;

    char* ws = (char*)d_ws;
    const size_t qkBytes = (size_t)NBATCH * NPOS * CQK * sizeof(_Float16);     //  2 MiB each
    const size_t vBytes  = (size_t)NBATCH * CDIM * NPOS * sizeof(_Float16);    // 16 MiB
    const size_t mlBytes = (size_t)2 * NBATCH * NPOS * sizeof(float);          // 128 KiB each (2 j-halves)
    const size_t xtBytes = (size_t)NBATCH * NPOS * CDIM * sizeof(_Float16);    // 16 MiB

    _Float16* Qp = (_Float16*)(ws);
    _Float16* Kp = (_Float16*)(ws + qkBytes);
    _Float16* Vp = (_Float16*)(ws + 2 * qkBytes);
    float* mArr  = (float*)(ws + 2 * qkBytes + vBytes);
    float* lArr  = (float*)(ws + 2 * qkBytes + vBytes + mlBytes);
    _Float16* Xt = (_Float16*)(ws + 2 * qkBytes + vBytes + 2 * mlBytes);
    _Float16* Wh = (_Float16*)(ws + 2 * qkBytes + vBytes + 2 * mlBytes + xtBytes);
    float* biasc = (float*)(ws + 2 * qkBytes + vBytes + 2 * mlBytes + xtBytes
                              + (size_t)640 * CDIM * sizeof(_Float16));
    // total ws use ~= 37.0 MiB

    w_cvt_kernel<<<dim3(640 * CDIM / 4 / 256), 256, 0, stream>>>(wq, bq, wk, bk, wv, bv, Wh, biasc);
    x_cvt_kernel<<<dim3(NPOS / 64, CDIM / 64, NBATCH), 256, 0, stream>>>(x, Xt);
    proj_gemm_kernel<<<dim3(NPOS / 256, 10, NBATCH), 256, 0, stream>>>(Wh, biasc, Xt, Qp, Kp, Vp);
    attn_stats_kernel<<<dim3(NPOS / 64, NBATCH, 2), 512, 0, stream>>>(Qp, Kp, mArr, lArr);
    attn_out_kernel<<<dim3(NPOS / 64 * NBATCH), 512, 0, stream>>>(x, Qp, Kp, Vp, mArr, lArr, gamma, out);
}